// Round 11
// baseline (280.838 us; speedup 1.0000x reference)
//
#include <hip/hip_runtime.h>
#include <stdint.h>

#define TT 512
#define BB 32
#define EE 512
#define HH 2048

typedef __attribute__((ext_vector_type(8))) short short8;   // 8 x bf16 (4 VGPRs)
typedef __attribute__((ext_vector_type(4))) float f32x4;    // MFMA accumulator

// LDS geometry (in shorts)
#define XROW 528            // 512 data + 16 pad: measured 0 bank conflicts;
                            // 520 gave 8.4M conflicts. Row stride 1056 B.
#define XBUF32 (32 * XROW)  // one 32-t chunk buffer = 16,896 shorts (33 KB)

static __device__ __forceinline__ float fast_exp(float x) {
    return __builtin_amdgcn_exp2f(x * 1.44269504f);
}
static __device__ __forceinline__ float fast_rcp(float x) {
    return __builtin_amdgcn_rcpf(x);
}

// Packed fp32->bf16 RNE convert: 1 instr per 2 elements.
static __device__ __forceinline__ unsigned cvtpk_bf16(float lo, float hi) {
    unsigned r;
    asm("v_cvt_pk_bf16_f32 %0, %1, %2" : "=v"(r) : "v"(lo), "v"(hi));
    return r;
}

// Async global->LDS DMA, 16 B/lane (wave-uniform LDS base + lane*16).
static __device__ __forceinline__ void load_lds16(const unsigned short* g, unsigned short* l) {
    __builtin_amdgcn_global_load_lds(
        (const __attribute__((address_space(1))) unsigned int*)(uintptr_t)g,
        (__attribute__((address_space(3))) unsigned int*)(uintptr_t)l,
        16, 0, 0);
}

// ---------------------------------------------------------------------------
// Pre-kernel (R9-verified): BW-optimal convert. Block-uniform X/W partition,
// 16 elems/thread, exact cover, max occupancy.
// ---------------------------------------------------------------------------
__launch_bounds__(256, 8)
__global__ void convert_inputs(const float* __restrict__ X,
                               const float* __restrict__ W,
                               unsigned short* __restrict__ Xb,
                               unsigned short* __restrict__ Wb) {
    // X: 8,388,608 elems = 2048 blocks * 4096; W: 3,145,728 = 768 blocks.
    const int bid = blockIdx.x;
    const float* src;
    unsigned short* dst;
    size_t base;
    if (bid < 2048) { src = X; dst = Xb; base = (size_t)bid * 4096; }
    else            { src = W; dst = Wb; base = (size_t)(bid - 2048) * 4096; }
    size_t j = base + (size_t)threadIdx.x * 16;

    float4 v0 = *(const float4*)(src + j);
    float4 v1 = *(const float4*)(src + j + 4);
    float4 v2 = *(const float4*)(src + j + 8);
    float4 v3 = *(const float4*)(src + j + 12);
    union { short8 s; unsigned u[4]; } o0, o1;
    o0.u[0] = cvtpk_bf16(v0.x, v0.y);
    o0.u[1] = cvtpk_bf16(v0.z, v0.w);
    o0.u[2] = cvtpk_bf16(v1.x, v1.y);
    o0.u[3] = cvtpk_bf16(v1.z, v1.w);
    o1.u[0] = cvtpk_bf16(v2.x, v2.y);
    o1.u[1] = cvtpk_bf16(v2.z, v2.w);
    o1.u[2] = cvtpk_bf16(v3.x, v3.y);
    o1.u[3] = cvtpk_bf16(v3.z, v3.w);
    *(short8*)(dst + j)     = o0.s;
    *(short8*)(dst + j + 8) = o1.s;
}

// ---------------------------------------------------------------------------
// Fused QRNN kernel — R14: gate-split (R10-verified) with 32-t regions:
// HALF the barriers (16 vs 32).
//
// Rationale: 9 structural variants (occupancy 20-41%, k/gate-split, counted
// vmcnt, straggler halving) all land 172-207 us with no pipe saturated.
// The one never-isolated lever (with staging intact) is SYNC FREQUENCY:
// every variant kept 32 barrier-convoys per block, and convoy/jitter loss
// appears in no pipe counter. This round: 32-t regions on the gate-split
// skeleton (the only structure whose exchange is small enough to afford
// double-size regions in fp32 at 2 blocks/CU).
//
// Block = 16 h, 4 waves: 3 GATE waves (one gate each, FULL K=512, W = 16
// frags = 64 AGPR pinned) + 1 SCAN wave (no W; bias + activations + scan +
// carry + vmax). Per region (ch = 0..15, 32 t):
//   gate: stage 8 DMA rows + 2 m-tile bursts (16 ds_read_b128 + 16 MFMA
//         each, a[8] reused) + 2 f32x4 publishes.
//   scan: 2 tails (m-tile A then B of chunk ch-1) from exchA/exchB.
// Scan role rotates with slot&3 (2 resident blocks -> adjacent slots ->
// scan waves on different SIMDs).
//
// LDS: X dbuf 2*XBUF32*2B = 67,584 + exchA/exchB 2*[2][64][12]*4B = 12,288
//   -> 79,872 B <= 81,920: exactly 2 blocks/CU. [64][12] stride 48 B is the
//   R1-verified conflict-free b128 layout.
//
// Hazards (R10-verified set, ch now 0..15):
//  (1) gates publish(ch) -> scan reads(ch) NEXT region: __syncthreads(ch)
//      (lgkm drained). Slot ch&1 republished region ch+2; scan's reads
//      retired at barrier(ch+1).
//  (2) X dbuf WAR/RAW: stage(ch+1) in region ch writes buf^1, consumed in
//      region ch+1 (vmcnt+lgkm drained at each __syncthreads); buf^1's
//      prior readers retired at barrier(ch-1).
//  (3) Barriers wave-uniform (ch uniform; role branches contain no barrier).
//  (4) carry/vmax private to the scan wave; gates carry no state.
// ---------------------------------------------------------------------------
__launch_bounds__(256, 2)
__global__ void qrnn_fused(const unsigned short* __restrict__ Xb, // bf16 (T,B,E)
                           const unsigned short* __restrict__ Wb, // bf16 (3H,E)
                           const float* __restrict__ bias,        // (3H)
                           float* __restrict__ out)               // (B,H) fp32
{
    __shared__ unsigned short xlds[2 * XBUF32];    // 67,584 B
    __shared__ float exchA[2][64][12];             //  6,144 B (m-tile A)
    __shared__ float exchB[2][64][12];             //  6,144 B (m-tile B)
                                                   // total 79,872 B

    const int tid  = threadIdx.x;
    const int wv   = tid >> 6;         // wave 0..3
    const int lane = tid & 63;
    const int q    = lane >> 4;        // quad 0..3
    const int c    = lane & 15;        // column within 16x16 tile (= h, = t)

    // XCD-aware swizzle: 4096 blocks = 8 XCDs x 4 batches x 128 h-groups.
    const int id   = blockIdx.x;       // 0..4095
    const int xcd  = id & 7;
    const int slot = id >> 3;          // 0..511 within this XCD
    const int b    = xcd * 4 + (slot >> 7);   // 4 batches per XCD
    const int hgrp = slot & 127;              // 128 h-groups (16 h) per batch
    const int h    = hgrp * 16 + c;

    // Role assignment: scan wave rotates by slot so co-resident blocks
    // put scan waves on different SIMDs.
    const int  scanwv = slot & 3;
    const bool isScan = (wv == scanwv);
    const int  gsel   = (wv < scanwv) ? wv : wv - 1;   // 0..2 for gate waves

    float carry = 0.0f;    // scan wave only
    float vmax  = -1e30f;  // scan wave only
    float b0 = 0.f, b1 = 0.f, b2 = 0.f;

    // ---- gate waves: preload this gate's FULL-K W row-frags; pin in AGPR --
    short8 wg[16];
    if (!isScan) {
        const unsigned short* wr = Wb + ((size_t)gsel * HH + h) * EE;
#pragma unroll
        for (int k = 0; k < 16; ++k)
            wg[k] = *(const short8*)(wr + k * 32 + q * 8);
#pragma unroll
        for (int k = 0; k < 16; ++k)
            asm volatile("" : "+a"(wg[k]));
    } else {
        b0 = bias[h];
        b1 = bias[HH + h];
        b2 = bias[2 * HH + h];
    }

    // ---- staging: wave wv owns rows wv*8 .. wv*8+7 of each 32-t chunk ----
    const unsigned short* g0 = Xb + ((size_t)(wv * 8) * BB + b) * EE + lane * 8;
    unsigned short* l0 = &xlds[(wv * 8) * XROW];

    auto stage = [&](int n, int slt) {
        const unsigned short* g = g0 + (size_t)n * (32 * BB * EE);
        unsigned short* l = l0 + slt * XBUF32;
#pragma unroll
        for (int i = 0; i < 8; ++i)
            load_lds16(g + (size_t)i * (BB * EE), l + i * XROW);
    };

    // tail (scan wave): activations + 16-step affine scan + carry + max.
    // Verbatim R1/R10-verified math; inputs bias-added by caller.
    auto do_tail = [&](f32x4 az, f32x4 af, f32x4 ao) {
        float aa[4], mm[4], oo[4];
#pragma unroll
        for (int r = 0; r < 4; ++r) {
            float e2 = fast_exp(2.0f * az[r]);
            float z  = 1.0f - 2.0f * fast_rcp(e2 + 1.0f);  // tanh
            float f  = fast_rcp(1.0f + fast_exp(-af[r]));  // sigmoid
            float o  = fast_rcp(1.0f + fast_exp(-ao[r]));  // sigmoid
            aa[r] = f * z;
            mm[r] = 1.0f - f;
            oo[r] = o;
        }

        float A = aa[0], M = mm[0];
#pragma unroll
        for (int r = 1; r < 4; ++r) { A = aa[r] + mm[r] * A; M = mm[r] * M; }

        float Ap = __shfl_up(A, 16, 64), Mp = __shfl_up(M, 16, 64);
        if (q >= 1) { A = A + M * Ap; M = M * Mp; }
        Ap = __shfl_up(A, 32, 64); Mp = __shfl_up(M, 32, 64);
        if (q >= 2) { A = A + M * Ap; M = M * Mp; }
        float Ae = __shfl_up(A, 16, 64), Me = __shfl_up(M, 16, 64);
        if (q == 0) { Ae = 0.0f; Me = 1.0f; }
        float cc = Ae + Me * carry;

#pragma unroll
        for (int r = 0; r < 4; ++r) {
            cc = aa[r] + mm[r] * cc;
            vmax = fmaxf(vmax, oo[r] * cc);
        }

        float cend = A + M * carry;
        carry = __shfl(cend, 48 + c, 64);
    };

    // scan-wave helper: one chunk-tail from an exchange array.
    auto scan_from = [&](const float* e) {
        f32x4 az = *(const f32x4*)(e);
        f32x4 af = *(const f32x4*)(e + 4);
        f32x4 ao = *(const f32x4*)(e + 8);
#pragma unroll
        for (int r = 0; r < 4; ++r) { az[r] += b0; af[r] += b1; ao[r] += b2; }
        do_tail(az, af, ao);
    };

    stage(0, 0);
    __syncthreads();

    for (int ch = 0; ch < 16; ++ch) {
        const int buf = ch & 1;
        if (ch < 15) stage(ch + 1, buf ^ 1);

        if (!isScan) {
            // ---- gate wave: 2 m-tile bursts, full K, a[8] reused ----
#pragma unroll
            for (int mt = 0; mt < 2; ++mt) {
                const unsigned short* Abase =
                    &xlds[buf * XBUF32 + (mt * 16 + c) * XROW + q * 8];
                f32x4 ac0 = {0.f, 0.f, 0.f, 0.f};
                f32x4 ac1 = {0.f, 0.f, 0.f, 0.f};
#pragma unroll
                for (int half = 0; half < 2; ++half) {
                    short8 a[8];
#pragma unroll
                    for (int j = 0; j < 8; ++j)
                        a[j] = *(const short8*)(Abase + (half * 8 + j) * 32);
#pragma unroll
                    for (int j = 0; j < 8; ++j) {
                        if (j & 1)
                            ac1 = __builtin_amdgcn_mfma_f32_16x16x32_bf16(a[j], wg[half * 8 + j], ac1, 0, 0, 0);
                        else
                            ac0 = __builtin_amdgcn_mfma_f32_16x16x32_bf16(a[j], wg[half * 8 + j], ac0, 0, 0, 0);
                    }
                }
                f32x4 ac = ac0 + ac1;
                float* e = mt ? &exchB[ch & 1][lane][gsel * 4]
                              : &exchA[ch & 1][lane][gsel * 4];
                *(f32x4*)(e) = ac;
            }
        } else {
            // ---- scan wave: tails for chunk ch-1 (m-tile A, then B) ----
            if (ch > 0) {
                scan_from(&exchA[(ch - 1) & 1][lane][0]);
                scan_from(&exchB[(ch - 1) & 1][lane][0]);
            }
        }

        __syncthreads();   // the ONE barrier per region (hazards 1-3)
    }

    // ---- epilogue: tails for chunk 15 (published in region 15) ----
    if (isScan) {
        scan_from(&exchA[15 & 1][lane][0]);
        scan_from(&exchB[15 & 1][lane][0]);

        vmax = fmaxf(vmax, __shfl_xor(vmax, 16, 64));
        vmax = fmaxf(vmax, __shfl_xor(vmax, 32, 64));
        if (q == 0) out[(size_t)b * HH + h] = vmax;
    }
}

// ---------------------------------------------------------------------------
extern "C" void kernel_launch(void* const* d_in, const int* in_sizes, int n_in,
                              void* d_out, int out_size, void* d_ws, size_t ws_size,
                              hipStream_t stream) {
    const float* sent = (const float*)d_in[0];
    // d_in[1] = lengths (unused by the math)
    const float* W    = (const float*)d_in[2];
    const float* bias = (const float*)d_in[3];
    float* out        = (float*)d_out;

    const int nX = TT * BB * EE;        // 8,388,608
    unsigned short* Xb = (unsigned short*)d_ws;
    unsigned short* Wb = Xb + nX;       // 16 MiB offset, 16B-aligned

    // X: 2048 blocks, W: 768 blocks (4096 elems each, exact cover)
    convert_inputs<<<2816, 256, 0, stream>>>(sent, W, Xb, Wb);

    dim3 grid(4096);                    // 8 xcd x 4 b x 128 hgrp (16 h each)
    qrnn_fused<<<grid, 256, 0, stream>>>(Xb, Wb, bias, out);
}